// Round 5
// baseline (230.044 us; speedup 1.0000x reference)
//
#include <hip/hip_runtime.h>
#include <hip/hip_bf16.h>

typedef __attribute__((ext_vector_type(4))) float f32x4;
typedef __attribute__((ext_vector_type(8))) short short8;
typedef __attribute__((ext_vector_type(8))) __bf16 bf16x8;

#define NDIM 172
#define EDIM 172
#define TDIM 100
#define KCAT 444   // 172+172+100
#define KPAD 512   // padded to 4 x 128
#define QDIM 272   // 172+100
#define ODIM 128
#define ZDIM 256
#define NNBR 32
#define BPB 4      // batch rows per fused block (M = 128)
#define KSTEP 128
#define NKS (KPAD / KSTEP)   // 4
#define LN_EPS 1e-5f

// ---- LDS layout (dynamic, 1 block/CU) ----
// [0, 32768)        A staging  [128 rows][256 B] swizzled      (GEMM phase)
// [32768, 98304)    W staging  [256 rows][256 B] swizzled      (GEMM phase)
// [0, 65536)        Z bf16     [128][256] ZB-swizzled          (tail, union)
// [98304, +2048)    qres [4][128] f32
// [100352, +1024)   Pband [4][2][32] f32
// [101376, +2048)   Obuf [4][128] f32
// [103424, +64)     red [8][2] f32
#define W_OFF 32768
#define SMEM_BYTES 103488

// Z_lds byte offset with XOR bank-swizzle (row stride 512 B)
#define ZB(r,c) ((((r) * 512) + ((c) * 2)) ^ (((r) & 7) << 4))

__device__ __forceinline__ unsigned short f2bf(float f) {
    unsigned u = __builtin_bit_cast(unsigned, f);
    u += 0x7fffu + ((u >> 16) & 1u);
    return (unsigned short)(u >> 16);
}
__device__ __forceinline__ float bf2f(unsigned short h) {
    unsigned u = ((unsigned)h) << 16;
    return __builtin_bit_cast(float, u);
}

// async global->LDS, 16 bytes per lane (lane-contiguous dest)
__device__ __forceinline__ void gll16(const void* g, void* l) {
    __builtin_amdgcn_global_load_lds(
        (const __attribute__((address_space(1))) unsigned int*)g,
        (__attribute__((address_space(3))) unsigned int*)l,
        16, 0, 0);
}

// ---- prep: wswz = Wkv bf16 pre-permuted per 128-K tile so that a LINEAR
// global_load_lds produces the XOR-swizzled LDS image the MFMA reads expect.
// Read swizzle: LDS byte = row*256 + ((kc ^ (row&15))<<4) + r  =>
// LDS byte L = row*256 + c*16 + r holds W[row][tile*128 + (c^(row&15))*8 + r/2].
// Also wqT bf16[272][128] (k-major, for q_proj) and woPk bf16[128][128]
// (row-major pack of Wo, for vectorized out-proj).
#define WKV_N (256 * KPAD)          // 131072 shorts (4 tiles x 32768)
#define WQT_N (QDIM * ODIM)         // 34816
#define WOPK_N (ODIM * ODIM)        // 16384
__global__ void prep_pack(const float* __restrict__ Wkv, const float* __restrict__ Wq,
                          const float* __restrict__ Wo,
                          unsigned short* __restrict__ wswz,
                          unsigned short* __restrict__ wqT,
                          unsigned short* __restrict__ woPk) {
    int idx = blockIdx.x * 256 + threadIdx.x;
    if (idx < WKV_N) {
        int tile = idx >> 15;            // 32768 shorts per K-tile
        int qb   = (idx & 32767) * 2;    // byte offset within tile's LDS image
        int row  = qb >> 8;              // W row (256 B per row)
        int x    = qb & 255;
        int c    = x >> 4;               // 16B chunk in row
        int e    = (x & 15) >> 1;        // bf16 element in chunk
        int k    = tile * KSTEP + ((c ^ (row & 15)) << 3) + e;
        wswz[idx] = f2bf((k < KCAT) ? Wkv[row * KCAT + k] : 0.f);
    } else if (idx < WKV_N + WQT_N) {
        int j = idx - WKV_N;
        int k = j >> 7, cc = j & 127;
        wqT[j] = f2bf(Wq[cc * QDIM + k]);
    } else if (idx < WKV_N + WQT_N + WOPK_N) {
        int j = idx - WKV_N - WQT_N;
        woPk[j] = f2bf(Wo[j]);           // Wo is [c][k] row-major already
    }
}

// ---- Q projection: Q[B,128] = concat(node,time) @ Wq^T + bq  (coalesced via wqT)
__global__ __launch_bounds__(256) void q_proj(
    const float* __restrict__ node_feat, const float* __restrict__ time_feat,
    const unsigned short* __restrict__ wqT, const float* __restrict__ bq,
    float* __restrict__ Qbuf) {
    __shared__ float x[8][QDIM];
    const int tid = threadIdx.x;
    const long b0 = (long)blockIdx.x * 8;
    for (int g = tid; g < 8 * QDIM; g += 256) {
        int r = g / QDIM, k = g - r * QDIM;
        x[r][k] = (k < NDIM) ? node_feat[(b0 + r) * NDIM + k]
                             : time_feat[(b0 + r) * TDIM + (k - NDIM)];
    }
    __syncthreads();
    const int c = tid & 127;
    const int rb = (tid >> 7) * 4;
    float s0 = bq[c], s1 = s0, s2 = s0, s3 = s0;
    #pragma unroll 8
    for (int k = 0; k < QDIM; k++) {
        float w = bf2f(wqT[k * 128 + c]);
        s0 += x[rb + 0][k] * w;
        s1 += x[rb + 1][k] * w;
        s2 += x[rb + 2][k] * w;
        s3 += x[rb + 3][k] * w;
    }
    Qbuf[(b0 + rb + 0) * 128 + c] = s0;
    Qbuf[(b0 + rb + 1) * 128 + c] = s1;
    Qbuf[(b0 + rb + 2) * 128 + c] = s2;
    Qbuf[(b0 + rb + 3) * 128 + c] = s3;
}

__global__ __launch_bounds__(1024, 4) void ta_fused(
    const float* __restrict__ edge_feat, const float* __restrict__ nbr_node,
    const float* __restrict__ nbr_time, const int* __restrict__ nbr_mask,
    const float* __restrict__ Qbuf,
    const unsigned short* __restrict__ wswz, const float* __restrict__ bkv,
    const unsigned short* __restrict__ woPk, const float* __restrict__ bo,
    const float* __restrict__ gamma, const float* __restrict__ beta,
    float* __restrict__ out)
{
    extern __shared__ __align__(16) unsigned char smem[];
    float* qres  = (float*)(smem + 98304);   // [4][128]
    float* Pband = (float*)(smem + 100352);  // [4][2][32]
    float* Obuf  = (float*)(smem + 101376);  // [4][128]
    float* red   = (float*)(smem + 103424);  // [8][2]

    const int tid  = threadIdx.x;
    const int lane = tid & 63;
    const int wid  = tid >> 6;
    const int b0   = blockIdx.x * BPB;

    // ---- GEMM: Z[128][256] = A[128][512] * Wkv[256][512]^T (zero-padded K)
    f32x4 acc[2][4];
    #pragma unroll
    for (int m = 0; m < 2; m++)
        #pragma unroll
        for (int n = 0; n < 4; n++) acc[m][n] = (f32x4){0.f, 0.f, 0.f, 0.f};

    const int wm = wid >> 2;   // 0..3 : 32-row band
    const int wn = wid & 3;    // 0..3 : 64-col band

    // per-thread A staging geometry: 4 chunks of 4 floats (128 rows x 32 grps)
    float4 areg[4];
    int rg[4], a_koff[4], a_byte[4];
    #pragma unroll
    for (int i = 0; i < 4; i++) {
        int g = i * 1024 + tid;
        int row = g >> 5, grp = g & 31;
        rg[i] = (b0 + (row >> 5)) * NNBR + (row & 31);
        a_koff[i] = grp * 4;
        a_byte[i] = row * 256 + (((grp >> 1) ^ (row & 15)) << 4) + ((grp & 1) << 3);
    }

    auto ISSUE_A = [&](int k0) {
        #pragma unroll
        for (int i = 0; i < 4; i++) {
            int k = k0 + a_koff[i];
            float4 v = make_float4(0.f, 0.f, 0.f, 0.f);
            if (k < NDIM)             v = *(const float4*)(nbr_node  + (size_t)rg[i] * NDIM + k);
            else if (k < NDIM + EDIM) v = *(const float4*)(edge_feat + (size_t)rg[i] * EDIM + (k - NDIM));
            else if (k < KCAT)        v = *(const float4*)(nbr_time  + (size_t)rg[i] * TDIM + (k - NDIM - EDIM));
            areg[i] = v;
        }
    };

    auto WRITE_A = [&]() {
        #pragma unroll
        for (int i = 0; i < 4; i++) {
            ushort4 h = make_ushort4(f2bf(areg[i].x), f2bf(areg[i].y),
                                     f2bf(areg[i].z), f2bf(areg[i].w));
            *(ushort4*)(smem + a_byte[i]) = h;
        }
    };

    auto GLL_W = [&](int ks) {
        #pragma unroll
        for (int j = 0; j < 4; j++) {
            int s = j * 1024 + tid;   // 16B chunk [0,4096)
            gll16(wswz + (size_t)ks * 32768 + s * 8, smem + W_OFF + s * 16);
        }
    };

    // prologue: A(0) regs + W(0) GLL, land both at one barrier
    ISSUE_A(0);
    GLL_W(0);
    WRITE_A();            // waits only on areg loads (GLLs keep flying)
    __syncthreads();      // drains W(0)

    #pragma unroll
    for (int ks = 0; ks < NKS; ks++) {
        if (ks < NKS - 1) ISSUE_A((ks + 1) * KSTEP);  // flies under ~900cyc compute
        // compute step ks: 4 x K=32 halves
        #pragma unroll
        for (int kk = 0; kk < 4; kk++) {
            const int kc = (kk * 64 + (lane >> 4) * 16) >> 4;  // 16B chunk idx in row
            bf16x8 af[2], bfr[4];
            #pragma unroll
            for (int m = 0; m < 2; m++) {
                int row = wm * 32 + m * 16 + (lane & 15);
                af[m] = __builtin_bit_cast(bf16x8,
                    *(const short8*)(smem + row * 256 + ((kc ^ (row & 15)) << 4)));
            }
            #pragma unroll
            for (int n = 0; n < 4; n++) {
                int row = wn * 64 + n * 16 + (lane & 15);   // W row = Z column
                bfr[n] = __builtin_bit_cast(bf16x8,
                    *(const short8*)(smem + W_OFF + row * 256 + ((kc ^ (row & 15)) << 4)));
            }
            #pragma unroll
            for (int m = 0; m < 2; m++)
                #pragma unroll
                for (int n = 0; n < 4; n++)
                    acc[m][n] = __builtin_amdgcn_mfma_f32_16x16x32_bf16(af[m], bfr[n], acc[m][n], 0, 0, 0);
        }
        __syncthreads();                 // drains areg loads (landed: ~900cyc elapsed)
        if (ks < NKS - 1) {
            GLL_W(ks + 1);               // W region free (all waves past barrier)
            WRITE_A();                   // regs already drained -> no stall
            __syncthreads();             // drains GLL (~250cyc residual)
        }
    }

    // ---- stage Q rows (coalesced) + dump Z (+bkv) to LDS bf16 (ZB swizzle)
    if (tid < BPB * ODIM) {
        int b = tid >> 7, c = tid & 127;
        qres[b * ODIM + c] = Qbuf[(long)(b0 + b) * ODIM + c];
    }
    #pragma unroll
    for (int n = 0; n < 4; n++) {
        int col = wn * 64 + n * 16 + (lane & 15);
        float bk = bkv[col];
        #pragma unroll
        for (int m = 0; m < 2; m++) {
            #pragma unroll
            for (int j = 0; j < 4; j++) {
                int row = wm * 32 + m * 16 + (lane >> 4) * 4 + j;
                *(unsigned short*)(smem + ZB(row, col)) = f2bf(acc[m][n][j] + bk);
            }
        }
    }
    __syncthreads();

    // ---- scores + softmax: waves 0..7 -> (b=wid>>1, h=wid&1); lane pair per n2
    if (wid < 2 * BPB) {
        int bl = wid >> 1, h = wid & 1;
        int n2 = lane >> 1, half = lane & 1;
        int np = h * 16 + (n2 >> 1);                  // Z row (mixed reshape)
        int rowZ = bl * NNBR + np;
        int cb = (n2 & 1) * 64 + half * 32;           // Z col base (K part)
        const float* q = qres + bl * ODIM + h * 64 + half * 32;
        float s = 0.f;
        #pragma unroll
        for (int j = 0; j < 4; j++) {
            short8 z8 = *(const short8*)(smem + ZB(rowZ, cb + j * 8));
            #pragma unroll
            for (int e = 0; e < 8; e++)
                s += q[j * 8 + e] * bf2f((unsigned short)z8[e]);
        }
        s += __shfl_xor(s, 1);
        s *= 0.125f;  // HEAD_DIM^-0.5
        if (nbr_mask[(long)(b0 + bl) * NNBR + n2] == 0) s = -1e10f;
        float mx = s;
        #pragma unroll
        for (int off = 1; off < 64; off <<= 1) mx = fmaxf(mx, __shfl_xor(mx, off));
        float e = __expf(s - mx);
        float sum = e;
        #pragma unroll
        for (int off = 1; off < 64; off <<= 1) sum += __shfl_xor(sum, off);
        float p = e * 2.f / sum;   // each n2 counted twice in sum
        if (half == 0) Pband[(bl * 2 + h) * NNBR + n2] = p;
    }
    __syncthreads();

    // ---- O = P @ V : one thread per (b, h*64+d)
    if (tid < BPB * ODIM) {
        int b = tid >> 7, c = tid & 127, h = c >> 6, d = c & 63;
        const float* P = Pband + (b * 2 + h) * NNBR;
        float s = 0.f;
        #pragma unroll
        for (int n2 = 0; n2 < NNBR; n2++) {
            int np = h * 16 + (n2 >> 1);
            int col = ODIM + (n2 & 1) * 64 + d;       // V part
            s += P[n2] * bf2f(*(const unsigned short*)(smem + ZB(b * NNBR + np, col)));
        }
        Obuf[b * ODIM + c] = s;
    }
    __syncthreads();

    // ---- out proj (vectorized woPk rows) + LayerNorm
    {
        int b = tid >> 7, c = tid & 127;
        float s = 0.f;
        if (tid < BPB * ODIM) {
            s = bo[c];
            const float* ob = Obuf + b * ODIM;
            const unsigned short* wr = woPk + c * ODIM;
            #pragma unroll
            for (int j = 0; j < 16; j++) {
                short8 w8 = *(const short8*)(wr + j * 8);
                float4 o0 = *(const float4*)(ob + j * 8);
                float4 o1 = *(const float4*)(ob + j * 8 + 4);
                s += o0.x * bf2f((unsigned short)w8[0]) + o0.y * bf2f((unsigned short)w8[1])
                   + o0.z * bf2f((unsigned short)w8[2]) + o0.w * bf2f((unsigned short)w8[3])
                   + o1.x * bf2f((unsigned short)w8[4]) + o1.y * bf2f((unsigned short)w8[5])
                   + o1.z * bf2f((unsigned short)w8[6]) + o1.w * bf2f((unsigned short)w8[7]);
            }
        }
        float s1 = s, s2 = s * s;
        #pragma unroll
        for (int off = 1; off < 64; off <<= 1) {
            s1 += __shfl_xor(s1, off);
            s2 += __shfl_xor(s2, off);
        }
        if (wid < 2 * BPB && lane == 0) { red[wid * 2] = s1; red[wid * 2 + 1] = s2; }
        __syncthreads();
        if (tid < BPB * ODIM) {
            float t1 = red[b * 4 + 0] + red[b * 4 + 2];
            float t2 = red[b * 4 + 1] + red[b * 4 + 3];
            float mu  = t1 * (1.f / 128.f);
            float var = t2 * (1.f / 128.f) - mu * mu;
            float inv = rsqrtf(var + LN_EPS);
            out[(long)(b0 + b) * ODIM + c] = (s - mu) * inv * gamma[c] + beta[c];
        }
    }
}

extern "C" void kernel_launch(void* const* d_in, const int* in_sizes, int n_in,
                              void* d_out, int out_size, void* d_ws, size_t ws_size,
                              hipStream_t stream) {
    const float* node_feat = (const float*)d_in[0];
    const float* time_feat = (const float*)d_in[1];
    const float* edge_feat = (const float*)d_in[2];
    const float* nbr_node  = (const float*)d_in[3];
    const float* nbr_time  = (const float*)d_in[4];
    const int*   nbr_mask  = (const int*)d_in[5];
    const float* Wq   = (const float*)d_in[6];
    const float* bq   = (const float*)d_in[7];
    const float* Wkv  = (const float*)d_in[8];
    const float* bkv  = (const float*)d_in[9];
    const float* Wo   = (const float*)d_in[10];
    const float* bo   = (const float*)d_in[11];
    const float* gma  = (const float*)d_in[12];
    const float* bta  = (const float*)d_in[13];
    float* out = (float*)d_out;

    const int B = in_sizes[0] / NDIM;  // 8192

    // workspace layout
    char* ws = (char*)d_ws;
    float* Qbuf = (float*)ws;                                   // B*128*4 = 4 MB
    unsigned short* wswz = (unsigned short*)(ws + (size_t)B * ODIM * 4);
    unsigned short* wqT  = wswz + WKV_N;
    unsigned short* woPk = wqT + WQT_N;

    // allow >64KB dynamic LDS (103.5 KB/block, 1 block/CU)
    static int attr_set = 0;
    (void)attr_set;
    hipFuncSetAttribute((const void*)ta_fused,
                        hipFuncAttributeMaxDynamicSharedMemorySize, SMEM_BYTES);

    const int prep_total = WKV_N + WQT_N + WOPK_N;
    prep_pack<<<dim3((prep_total + 255) / 256), dim3(256), 0, stream>>>(
        Wkv, Wq, Wo, wswz, wqT, woPk);
    q_proj<<<dim3(B / 8), dim3(256), 0, stream>>>(node_feat, time_feat, wqT, bq, Qbuf);
    ta_fused<<<dim3(B / BPB), dim3(1024), SMEM_BYTES, stream>>>(
        edge_feat, nbr_node, nbr_time, nbr_mask, Qbuf,
        wswz, bkv, woPk, bo, gma, bta, out);
}

// Round 6
// 216.760 us; speedup vs baseline: 1.0613x; 1.0613x over previous
//
#include <hip/hip_runtime.h>
#include <hip/hip_bf16.h>

typedef __attribute__((ext_vector_type(4))) float f32x4;
typedef __attribute__((ext_vector_type(8))) short short8;
typedef __attribute__((ext_vector_type(8))) __bf16 bf16x8;

#define NDIM 172
#define EDIM 172
#define TDIM 100
#define KCAT 444   // 172+172+100
#define KPAD 448
#define QDIM 272   // 172+100
#define ODIM 128
#define ZDIM 256
#define NNBR 32
#define BPB 2      // batch rows per fused block (M = 64)
#define KSTEP 64
#define NKS (KPAD / KSTEP)   // 7
#define LN_EPS 1e-5f

// LDS: Abuf [0,8K) ; Wbuf0 [8K,40K) ; Wbuf1 [40K,72K) ; Z bf16 [64][256] in [0,32K) after GEMM
#define W0_OFF 8192
#define W1_OFF 40960

// Z_lds byte offset with XOR bank-swizzle (row stride 512 B)
#define ZB(r,c) ((((r) * 512) + ((c) * 2)) ^ (((r) & 7) << 4))

// raw barrier: drains LDS ops only, leaves vmcnt (global/GLL prefetch) in flight
#define BARRIER() do { \
    asm volatile("s_waitcnt lgkmcnt(0)\ns_barrier" ::: "memory"); \
    __builtin_amdgcn_sched_barrier(0); \
} while (0)

__device__ __forceinline__ unsigned short f2bf(float f) {
    unsigned u = __builtin_bit_cast(unsigned, f);
    u += 0x7fffu + ((u >> 16) & 1u);
    return (unsigned short)(u >> 16);
}
__device__ __forceinline__ float bf2f(unsigned short h) {
    unsigned u = ((unsigned)h) << 16;
    return __builtin_bit_cast(float, u);
}

// async global->LDS, 16 bytes per lane (lane-contiguous dest)
__device__ __forceinline__ void gll16(const void* g, void* l) {
    __builtin_amdgcn_global_load_lds(
        (const __attribute__((address_space(1))) unsigned int*)g,
        (__attribute__((address_space(3))) unsigned int*)l,
        16, 0, 0);
}

// ---- prep: wswz = Wkv bf16, pre-permuted per 64-K tile so that a LINEAR
// global_load_lds produces the XOR-swizzled LDS image the MFMA reads expect.
// Also WqT bf16[272][128], WoT bf16[128][128] (k-major).
#define WKV_N (256 * KPAD)          // 114688 shorts (7 tiles x 16384)
#define WQT_N (QDIM * ODIM)         // 34816
#define WOT_N (ODIM * ODIM)         // 16384
__global__ void prep_pack(const float* __restrict__ Wkv, const float* __restrict__ Wq,
                          const float* __restrict__ Wo,
                          unsigned short* __restrict__ wswz,
                          unsigned short* __restrict__ wqT,
                          unsigned short* __restrict__ woT) {
    int idx = blockIdx.x * 256 + threadIdx.x;
    if (idx < WKV_N) {
        int tile = idx >> 14;            // 16384 shorts per K-tile
        int qb   = (idx & 16383) * 2;    // byte offset within tile's LDS image
        int row  = qb >> 7;              // W row (128 B per row)
        int x    = qb & 127;
        int f8   = (x ^ ((row & 7) << 4)) >> 4;   // inverse of the read swizzle
        int e    = (x & 15) >> 1;
        int k    = tile * KSTEP + f8 * 8 + e;
        wswz[idx] = f2bf((k < KCAT) ? Wkv[row * KCAT + k] : 0.f);
    } else if (idx < WKV_N + WQT_N) {
        int j = idx - WKV_N;
        int k = j >> 7, c = j & 127;
        wqT[j] = f2bf(Wq[c * QDIM + k]);
    } else if (idx < WKV_N + WQT_N + WOT_N) {
        int j = idx - WKV_N - WQT_N;
        int k = j >> 7, c = j & 127;
        woT[j] = f2bf(Wo[c * ODIM + k]);
    }
}

// ---- Q projection: Q[B,128] = concat(node,time) @ Wq^T + bq  (coalesced via wqT)
__global__ __launch_bounds__(256) void q_proj(
    const float* __restrict__ node_feat, const float* __restrict__ time_feat,
    const unsigned short* __restrict__ wqT, const float* __restrict__ bq,
    float* __restrict__ Qbuf) {
    __shared__ float x[8][QDIM];
    const int tid = threadIdx.x;
    const long b0 = (long)blockIdx.x * 8;
    for (int g = tid; g < 8 * QDIM; g += 256) {
        int r = g / QDIM, k = g - r * QDIM;
        x[r][k] = (k < NDIM) ? node_feat[(b0 + r) * NDIM + k]
                             : time_feat[(b0 + r) * TDIM + (k - NDIM)];
    }
    __syncthreads();
    const int c = tid & 127;
    const int rb = (tid >> 7) * 4;
    float s0 = bq[c], s1 = s0, s2 = s0, s3 = s0;
    #pragma unroll 8
    for (int k = 0; k < QDIM; k++) {
        float w = bf2f(wqT[k * 128 + c]);
        s0 += x[rb + 0][k] * w;
        s1 += x[rb + 1][k] * w;
        s2 += x[rb + 2][k] * w;
        s3 += x[rb + 3][k] * w;
    }
    Qbuf[(b0 + rb + 0) * 128 + c] = s0;
    Qbuf[(b0 + rb + 1) * 128 + c] = s1;
    Qbuf[(b0 + rb + 2) * 128 + c] = s2;
    Qbuf[(b0 + rb + 3) * 128 + c] = s3;
}

__global__ __launch_bounds__(512, 4) void ta_fused(
    const float* __restrict__ edge_feat, const float* __restrict__ nbr_node,
    const float* __restrict__ nbr_time, const int* __restrict__ nbr_mask,
    const float* __restrict__ Qbuf,
    const unsigned short* __restrict__ wswz, const float* __restrict__ bkv,
    const unsigned short* __restrict__ woT, const float* __restrict__ bo,
    const float* __restrict__ gamma, const float* __restrict__ beta,
    float* __restrict__ out)
{
    __shared__ __align__(16) unsigned char smem[73728];
    __shared__ float qres[BPB][ODIM];
    __shared__ float Pband[BPB][2][NNBR];
    __shared__ float Obuf[BPB][ODIM];
    __shared__ float red[4][2];

    const int tid  = threadIdx.x;
    const int lane = tid & 63;
    const int wid  = tid >> 6;
    const int b0   = blockIdx.x * BPB;

    // ---- stage precomputed Q rows (coalesced, 256 floats)
    if (tid < BPB * ODIM) {
        int b = tid >> 7, c = tid & 127;
        qres[b][c] = Qbuf[(long)(b0 + b) * ODIM + c];
    }

    // ---- GEMM: Z[64][256] = A[64][448] * Wkv[256][448]^T
    f32x4 acc[2][4];
    #pragma unroll
    for (int m = 0; m < 2; m++)
        #pragma unroll
        for (int n = 0; n < 4; n++) acc[m][n] = (f32x4){0.f, 0.f, 0.f, 0.f};

    const int wm = wid >> 2;   // 0..1 : 32-row band
    const int wn = wid & 3;    // 0..3 : 64-col band

    // per-thread A staging geometry (hoisted)
    const float* pN[2]; const float* pE[2]; const float* pT[2];
    int a_koff[2], a_byte[2];
    #pragma unroll
    for (int i = 0; i < 2; i++) {
        int g = i * 512 + tid;            // [0,1024): 64 rows x 16 float4-groups
        int row = g >> 4, grp = g & 15;
        int bl = row >> 5, n = row & 31;
        long rg = (long)(b0 + bl) * NNBR + n;
        pN[i] = nbr_node  + rg * NDIM;
        pE[i] = edge_feat + rg * EDIM;
        pT[i] = nbr_time  + rg * TDIM;
        a_koff[i] = grp * 4;
        a_byte[i] = (row * 128 + grp * 8) ^ ((row & 7) << 4);
    }

    float4 aregA[2], aregB[2];

    auto ISSUE_A = [&](int k0, float4* ar) {
        #pragma unroll
        for (int i = 0; i < 2; i++) {
            int k = k0 + a_koff[i];
            float4 v = make_float4(0.f, 0.f, 0.f, 0.f);
            if (k < NDIM)             v = *(const float4*)(pN[i] + k);
            else if (k < NDIM + EDIM) v = *(const float4*)(pE[i] + (k - NDIM));
            else if (k < KCAT)        v = *(const float4*)(pT[i] + (k - NDIM - EDIM));
            ar[i] = v;
        }
    };
    auto WRITE_A = [&](const float4* ar) {
        #pragma unroll
        for (int i = 0; i < 2; i++) {
            ushort4 h = make_ushort4(f2bf(ar[i].x), f2bf(ar[i].y),
                                     f2bf(ar[i].z), f2bf(ar[i].w));
            *(ushort4*)(smem + a_byte[i]) = h;
        }
    };
    auto GLL_W = [&](int t) {   // W tile t -> Wbuf[t&1]
        unsigned char* base = smem + ((t & 1) ? W1_OFF : W0_OFF);
        #pragma unroll
        for (int j = 0; j < 4; j++) {
            int s = j * 512 + tid;   // 16B chunk index [0,2048)
            gll16(wswz + (size_t)t * 16384 + s * 8, base + s * 16);
        }
    };
    auto COMPUTE = [&](const unsigned char* wbase) {
        #pragma unroll
        for (int kk = 0; kk < 2; kk++) {
            const int kb = kk * 64 + (lane >> 4) * 16;
            bf16x8 af[2], bfr[4];
            #pragma unroll
            for (int m = 0; m < 2; m++) {
                int row = wm * 32 + m * 16 + (lane & 15);
                int byte = (row * 128 + kb) ^ ((row & 7) << 4);
                af[m] = __builtin_bit_cast(bf16x8, *(const short8*)(smem + byte));
            }
            #pragma unroll
            for (int n = 0; n < 4; n++) {
                int row = wn * 64 + n * 16 + (lane & 15);   // W row = Z column
                int byte = (row * 128 + kb) ^ ((row & 7) << 4);
                bfr[n] = __builtin_bit_cast(bf16x8, *(const short8*)(wbase + byte));
            }
            #pragma unroll
            for (int m = 0; m < 2; m++)
                #pragma unroll
                for (int n = 0; n < 4; n++)
                    acc[m][n] = __builtin_amdgcn_mfma_f32_16x16x32_bf16(af[m], bfr[n], acc[m][n], 0, 0, 0);
        }
    };

    // ---- prologue: W(0),W(1) in flight; A(0) written; A(1) in regs
    GLL_W(0);
    ISSUE_A(0, aregA);
    WRITE_A(aregA);            // auto vmcnt wait: W(0)+A(0) landed (one-time ~900cyc)
    GLL_W(1);
    ISSUE_A(KSTEP, aregA);     // A(1)
    BARRIER();                 // W(1)+A(1) stay in flight

    #pragma unroll
    for (int ks = 0; ks < NKS; ks++) {
        COMPUTE(smem + ((ks & 1) ? W1_OFF : W0_OFF));
        if (ks < NKS - 1) {
            BARRIER();                       // Abuf + Wbuf[ks&1] now free; nothing drained
            if (ks < NKS - 2) {
                GLL_W(ks + 2);               // -> Wbuf[ks&1] (just freed)
                ISSUE_A((ks + 2) * KSTEP, (ks & 1) ? aregA : aregB);
            }
            // write A(ks+1): auto COUNTED vmcnt (A(ks+1) older than just-issued ops)
            WRITE_A((ks & 1) ? aregB : aregA);
            BARRIER();                       // A(ks+2)/W(ks+2) still in flight
        }
    }
    __syncthreads();   // nothing in flight; full drain OK

    // ---- dump Z (+bkv) to LDS as bf16 (ZB swizzle); C/D: col=lane&15, row=(lane>>4)*4+j
    #pragma unroll
    for (int n = 0; n < 4; n++) {
        int col = wn * 64 + n * 16 + (lane & 15);
        float bk = bkv[col];
        #pragma unroll
        for (int m = 0; m < 2; m++) {
            #pragma unroll
            for (int j = 0; j < 4; j++) {
                int row = wm * 32 + m * 16 + (lane >> 4) * 4 + j;
                *(unsigned short*)(smem + ZB(row, col)) = f2bf(acc[m][n][j] + bk);
            }
        }
    }
    __syncthreads();

    // ---- scores + softmax: waves 0..3 -> (b=wid>>1, h=wid&1); lane pair per n2
    if (wid < 2 * BPB) {
        int bl = wid >> 1, h = wid & 1;
        int n2 = lane >> 1, half = lane & 1;
        int np = h * 16 + (n2 >> 1);                  // Z row (mixed reshape)
        int rowZ = bl * NNBR + np;
        int cb = (n2 & 1) * 64 + half * 32;           // Z col base (K part)
        const float* q = &qres[bl][h * 64 + half * 32];
        float s = 0.f;
        #pragma unroll
        for (int j = 0; j < 4; j++) {
            short8 z8 = *(const short8*)(smem + ZB(rowZ, cb + j * 8));
            #pragma unroll
            for (int e = 0; e < 8; e++)
                s += q[j * 8 + e] * bf2f((unsigned short)z8[e]);
        }
        s += __shfl_xor(s, 1);
        s *= 0.125f;  // HEAD_DIM^-0.5
        if (nbr_mask[(long)(b0 + bl) * NNBR + n2] == 0) s = -1e10f;
        float mx = s;
        #pragma unroll
        for (int off = 1; off < 64; off <<= 1) mx = fmaxf(mx, __shfl_xor(mx, off));
        float e = __expf(s - mx);
        float sum = e;
        #pragma unroll
        for (int off = 1; off < 64; off <<= 1) sum += __shfl_xor(sum, off);
        float p = e * 2.f / sum;   // each n2 counted twice in sum
        if (half == 0) Pband[bl][h][n2] = p;
    }
    __syncthreads();

    // ---- O = P @ V : one thread per (b, h*64+d)
    if (tid < BPB * ODIM) {
        int b = tid >> 7, c = tid & 127, h = c >> 6, d = c & 63;
        const float* P = Pband[b][h];
        float s = 0.f;
        #pragma unroll
        for (int n2 = 0; n2 < NNBR; n2++) {
            int np = h * 16 + (n2 >> 1);
            int col = ODIM + (n2 & 1) * 64 + d;       // V part
            s += P[n2] * bf2f(*(const unsigned short*)(smem + ZB(b * NNBR + np, col)));
        }
        Obuf[b][c] = s;
    }
    __syncthreads();

    // ---- out proj (coalesced via WoT) + LayerNorm
    {
        int b = tid >> 7, c = tid & 127;
        float s = 0.f;
        if (tid < BPB * ODIM) {
            s = bo[c];
            const float* ob = Obuf[b];
            #pragma unroll 8
            for (int k = 0; k < ODIM; k++)
                s += ob[k] * bf2f(woT[k * 128 + c]);
        }
        float s1 = s, s2 = s * s;
        #pragma unroll
        for (int off = 1; off < 64; off <<= 1) {
            s1 += __shfl_xor(s1, off);
            s2 += __shfl_xor(s2, off);
        }
        if (wid < 2 * BPB && lane == 0) { red[wid][0] = s1; red[wid][1] = s2; }
        __syncthreads();
        if (tid < BPB * ODIM) {
            float t1 = red[b * 2][0] + red[b * 2 + 1][0];
            float t2 = red[b * 2][1] + red[b * 2 + 1][1];
            float mu  = t1 * (1.f / 128.f);
            float var = t2 * (1.f / 128.f) - mu * mu;
            float inv = rsqrtf(var + LN_EPS);
            out[(long)(b0 + b) * ODIM + c] = (s - mu) * inv * gamma[c] + beta[c];
        }
    }
}

extern "C" void kernel_launch(void* const* d_in, const int* in_sizes, int n_in,
                              void* d_out, int out_size, void* d_ws, size_t ws_size,
                              hipStream_t stream) {
    const float* node_feat = (const float*)d_in[0];
    const float* time_feat = (const float*)d_in[1];
    const float* edge_feat = (const float*)d_in[2];
    const float* nbr_node  = (const float*)d_in[3];
    const float* nbr_time  = (const float*)d_in[4];
    const int*   nbr_mask  = (const int*)d_in[5];
    const float* Wq   = (const float*)d_in[6];
    const float* bq   = (const float*)d_in[7];
    const float* Wkv  = (const float*)d_in[8];
    const float* bkv  = (const float*)d_in[9];
    const float* Wo   = (const float*)d_in[10];
    const float* bo   = (const float*)d_in[11];
    const float* gma  = (const float*)d_in[12];
    const float* bta  = (const float*)d_in[13];
    float* out = (float*)d_out;

    const int B = in_sizes[0] / NDIM;  // 8192

    // workspace layout
    char* ws = (char*)d_ws;
    float* Qbuf = (float*)ws;                                   // B*128*4 = 4 MB
    unsigned short* wswz = (unsigned short*)(ws + (size_t)B * ODIM * 4);
    unsigned short* wqT  = wswz + WKV_N;
    unsigned short* woT  = wqT + WQT_N;

    const int prep_total = WKV_N + WQT_N + WOT_N;
    prep_pack<<<dim3((prep_total + 255) / 256), dim3(256), 0, stream>>>(
        Wkv, Wq, Wo, wswz, wqT, woT);
    q_proj<<<dim3(B / 8), dim3(256), 0, stream>>>(node_feat, time_feat, wqT, bq, Qbuf);
    ta_fused<<<dim3(B / BPB), dim3(512), 0, stream>>>(
        edge_feat, nbr_node, nbr_time, nbr_mask, Qbuf,
        wswz, bkv, woT, bo, gma, bta, out);
}